// Round 4
// baseline (229.664 us; speedup 1.0000x reference)
//
#include <hip/hip_runtime.h>
#include <math.h>

// Problem constants
constexpr int Bn  = 2;
constexpr int Sn  = 4096;
constexpr int En  = 1024;
constexpr int Hn  = 16;
constexpr int Mtot = Bn * Sn;             // 8192
constexpr int Kp  = 1024;                 // GEMM K (fp16 single precision)
constexpr int PAD = 72;                   // LDS row stride (bf16), 144 B = 9x16B

typedef __bf16    bf16x8 __attribute__((ext_vector_type(8)));
typedef __bf16    bf16x4 __attribute__((ext_vector_type(4)));
typedef _Float16  f16x8  __attribute__((ext_vector_type(8)));
typedef _Float16  f16x4  __attribute__((ext_vector_type(4)));
typedef float     f32x4  __attribute__((ext_vector_type(4)));

// ---------------- fp32 -> fp16 conversion ----------------
__global__ void __launch_bounds__(256)
cvt_hs_kernel(const float* __restrict__ hs, _Float16* __restrict__ hs16)
{
    int t = blockIdx.x * 256 + threadIdx.x;
    int m = t >> 8;
    int k = (t & 255) << 2;
    float4 x = *(const float4*)&hs[((size_t)m << 10) + k];
    f16x4 h;
    h[0] = (_Float16)x.x; h[1] = (_Float16)x.y;
    h[2] = (_Float16)x.z; h[3] = (_Float16)x.w;
    *(f16x4*)&hs16[((size_t)m << 10) + k] = h;
}

__global__ void __launch_bounds__(256)
cvt_w_kernel(const float* __restrict__ qw, const float* __restrict__ kw,
             const float* __restrict__ vw, _Float16* __restrict__ w16)
{
    int t = blockIdx.x * 256 + threadIdx.x;
    int gn = t >> 8;
    int k  = (t & 255) << 2;
    int p  = gn >> 10, n = gn & 1023;
    const float* src = (p == 0) ? qw : (p == 1) ? kw : vw;
    float4 x = *(const float4*)&src[((size_t)n << 10) + k];
    f16x4 h;
    h[0] = (_Float16)x.x; h[1] = (_Float16)x.y;
    h[2] = (_Float16)x.z; h[3] = (_Float16)x.w;
    *(f16x4*)&w16[((size_t)gn << 10) + k] = h;
}

// ---------------- QKV projection: 256x256-tile 8-wave MFMA GEMM -------------
// v5: 256^2 tile / 8 waves (512 thr) / BK=64 / double-buffered 128KB LDS,
// 4-phase counted-vmcnt schedule (T2+T3+T4+T5, m201 geometry).
// Why: the 128^2 tile is LDS-BW-bound (per K-step: 48KB LDS traffic ~375cyc
// vs 310cyc MFMA wall) -- no schedule can fix the byte ratio (r1-r3 all
// neutral at ~567 TF). 256^2 halves per-FLOP LDS traffic: per K-tile 192KB
// reads ~1500cyc vs 2480cyc MFMA wall -> MFMA-bound.
// Phases per K-tile kt (rb=kt&1 read, wb=rb^1 staged for kt+1):
//   p0: ds_read af[0..3],bf[0..3] (kc0) | stage 4 A-loads -> wb | bar |
//       16 MFMA (ti0-3 x tj0-3, kc0) | bar
//   p1: ds_read af[4..7] (kc0)         | stage 4 B-loads -> wb | bar |
//       16 MFMA (ti4-7, kc0)           | bar
//   p2: ds_read af[0..3],bf[0..3] (kc1)                        | bar |
//       16 MFMA (ti0-3, kc1)           | bar
//   p3: ds_read af[4..7] (kc1)                                 | bar |
//       16 MFMA (ti4-7, kc1)  | vmcnt(0)+bar  <- only vm wait, ~3 phases flight
// LDS XOR swizzle: stored chunk s of row r holds global 16B-chunk s^(r&7)
// (pre-swizzled GLOBAL source, linear LDS dest -- m173 pattern); frag read
// chunk = (kc*4+quad)^(mrow&7) -> <=2-way bank aliasing (free, m136).
__device__ inline void load_lds16(const void* g, void* s) {
    __builtin_amdgcn_global_load_lds((const __attribute__((address_space(1))) void*)g,
                                     (__attribute__((address_space(3))) void*)s,
                                     16, 0, 0);
}

__device__ inline void block_sync() {
    asm volatile("" ::: "memory");
    __builtin_amdgcn_s_barrier();
    asm volatile("" ::: "memory");
}
__device__ inline void block_sync_vm0() {
    asm volatile("s_waitcnt vmcnt(0)" ::: "memory");
    __builtin_amdgcn_s_barrier();
    asm volatile("" ::: "memory");
}

template<int PM>   // 0 = q|k (swapped operands), 1 = v
__global__ void __launch_bounds__(512, 2)
qkv_mfma_kernel(const _Float16* __restrict__ A2, const _Float16* __restrict__ B2,
                const float* __restrict__ qb, const float* __restrict__ kb,
                const float* __restrict__ vb,
                __bf16* __restrict__ q16, __bf16* __restrict__ k16,
                __bf16* __restrict__ vt16, int n0base)
{
    __shared__ _Float16 As[2][256 * 64];   // 32KB per buffer
    __shared__ _Float16 Bs[2][256 * 64];   // total LDS = 128KB

    const int tid  = threadIdx.x;
    const int w    = tid >> 6;             // 0..7
    const int lane = tid & 63;
    const int wm   = w >> 2, wn = w & 3;   // 2M x 4N wave grid
    const int mrow = lane & 15, quad = lane >> 4;
    const int m0   = blockIdx.x * 256;             // seq tile
    const int n0   = n0base + blockIdx.y * 256;    // feature tile

    // staging: lane l -> LDS row (base + l>>3), chunk l&7 (linear dest);
    // global chunk = (l&7) ^ (l>>3)  (inverse swizzle on the source)
    const int subrow = lane >> 3;          // 0..7
    const int g8     = ((lane & 7) ^ subrow) * 8;   // f16 offset of 16B chunk
    const _Float16* Ag = A2 + (size_t)(m0 + w * 32 + subrow) * Kp + g8;
    const _Float16* Bg = B2 + (size_t)(n0 + w * 32 + subrow) * Kp + g8;

    // frag read: row = (wm*128|wn*64) + t*16 + mrow; chunk = (kc*4+quad)^(mrow&7)
    const int arow = wm * 128 + mrow;
    const int brow = wn * 64 + mrow;
    const int cx   = quad ^ (mrow & 7);    // kc0 chunk; kc1 chunk = cx^4

    f32x4 acc[8][4] = {};

    auto stageA = [&](int kt, int bi) {
        const int k0 = kt * 64;
#pragma unroll
        for (int l = 0; l < 4; l++)
            load_lds16(Ag + (size_t)l * 8 * Kp + k0, &As[bi][(w * 32 + l * 8) * 64]);
    };
    auto stageB = [&](int kt, int bi) {
        const int k0 = kt * 64;
#pragma unroll
        for (int l = 0; l < 4; l++)
            load_lds16(Bg + (size_t)l * 8 * Kp + k0, &Bs[bi][(w * 32 + l * 8) * 64]);
    };
    auto ladder = [&](const f16x8* AF, const f16x8* BF, int r0) {
        __builtin_amdgcn_s_setprio(1);
#pragma unroll
        for (int ti = 0; ti < 4; ti++)
#pragma unroll
            for (int tj = 0; tj < 4; tj++) {
                if (PM == 0)   // C[m=feature][n=seq]
                    acc[r0 + ti][tj] = __builtin_amdgcn_mfma_f32_16x16x32_f16(
                        BF[tj], AF[ti], acc[r0 + ti][tj], 0, 0, 0);
                else           // C[m=seq][n=feature]
                    acc[r0 + ti][tj] = __builtin_amdgcn_mfma_f32_16x16x32_f16(
                        AF[ti], BF[tj], acc[r0 + ti][tj], 0, 0, 0);
            }
        __builtin_amdgcn_s_setprio(0);
    };

    constexpr int NT = Kp / 64;            // 16 K-tiles

    stageA(0, 0);
    stageB(0, 0);
    block_sync_vm0();

    for (int kt = 0; kt < NT; ++kt) {
        const int rb = kt & 1, wb = rb ^ 1;
        const _Float16* AsR = &As[rb][0];
        const _Float16* BsR = &Bs[rb][0];
        f16x8 af[4], bf[4];

        // ---- p0: kc0, ti0-3 ----
#pragma unroll
        for (int t = 0; t < 4; t++)
            af[t] = *(const f16x8*)&AsR[(arow + t * 16) * 64 + cx * 8];
#pragma unroll
        for (int t = 0; t < 4; t++)
            bf[t] = *(const f16x8*)&BsR[(brow + t * 16) * 64 + cx * 8];
        if (kt + 1 < NT) stageA(kt + 1, wb);
        block_sync();
        ladder(af, bf, 0);
        block_sync();

        // ---- p1: kc0, ti4-7 ----
#pragma unroll
        for (int t = 0; t < 4; t++)
            af[t] = *(const f16x8*)&AsR[(arow + 64 + t * 16) * 64 + cx * 8];
        if (kt + 1 < NT) stageB(kt + 1, wb);
        block_sync();
        ladder(af, bf, 4);
        block_sync();

        // ---- p2: kc1, ti0-3 ----
#pragma unroll
        for (int t = 0; t < 4; t++)
            af[t] = *(const f16x8*)&AsR[(arow + t * 16) * 64 + (cx ^ 4) * 8];
#pragma unroll
        for (int t = 0; t < 4; t++)
            bf[t] = *(const f16x8*)&BsR[(brow + t * 16) * 64 + (cx ^ 4) * 8];
        block_sync();
        ladder(af, bf, 0);
        block_sync();

        // ---- p3: kc1, ti4-7 ----
#pragma unroll
        for (int t = 0; t < 4; t++)
            af[t] = *(const f16x8*)&AsR[(arow + 64 + t * 16) * 64 + (cx ^ 4) * 8];
        block_sync();
        ladder(af, bf, 4);
        // tile-end: drain this wave's prefetch (issued p0/p1, ~3 phases of
        // flight) then rally -- the ONLY vm wait in the loop
        block_sync_vm0();
    }

    if (PM == 0) {
        // acc[ti][tj]: row (quad*4+r) = feature, col (mrow) = seq
        const int p = n0 >> 10;                    // 0=q, 1=k
        const float* bptr = (p == 0) ? qb : kb;
        __bf16* dst = (p == 0) ? q16 : k16;
        const float scl = (p == 0) ? 0.125f : 1.0f;
#pragma unroll
        for (int ti = 0; ti < 8; ti++) {
            const int m  = m0 + wm * 128 + ti * 16 + mrow;   // seq
            const int bb = m >> 12, ss = m & 4095;
#pragma unroll
            for (int tj = 0; tj < 4; tj++) {
                const int fl = (n0 + wn * 64 + tj * 16 + quad * 4) & 1023;
                const int hh = fl >> 6, dd = fl & 63;        // dd..dd+3
                const float4 bv = *(const float4*)&bptr[fl];
                bf16x4 o;
                o[0] = (__bf16)((acc[ti][tj][0] + bv.x) * scl);
                o[1] = (__bf16)((acc[ti][tj][1] + bv.y) * scl);
                o[2] = (__bf16)((acc[ti][tj][2] + bv.z) * scl);
                o[3] = (__bf16)((acc[ti][tj][3] + bv.w) * scl);
                *(bf16x4*)&dst[((size_t)(bb * Hn + hh) * Sn + ss) * 64 + dd] = o;
            }
        }
    } else {
        // acc[ti][tj]: row (quad*4+r) = seq, col (mrow) = feature; V^T layout
#pragma unroll
        for (int tj = 0; tj < 4; tj++) {
            const int n  = n0 + wn * 64 + tj * 16 + mrow;
            const float bv = vb[n & 1023];
            const int hh = (n & 1023) >> 6, dd = n & 63;
#pragma unroll
            for (int ti = 0; ti < 8; ti++) {
                const int m  = m0 + wm * 128 + ti * 16 + quad * 4;   // + r
                const int bb = m >> 12, ss = m & 4095;
                bf16x4 pv4;
#pragma unroll
                for (int r = 0; r < 4; r++)
                    pv4[r] = (__bf16)(acc[ti][tj][r] + bv);
                *(bf16x4*)&vt16[((size_t)(bb * Hn + hh) * 64 + dd) * Sn + ss] = pv4;
            }
        }
    }
}

// ---------------- Banded attention: MFMA, double-buffered staging -----------
// Block = 256 queries (4 waves x 64). S^T = K.Q^T ; O^T = V^T.P^T.
// ONE barrier per subtile: compute reads buf[st&1] while regs hold st+1 data;
// writes go to buf[(st+1)&1], whose last readers synced at the st-1 barrier.
__global__ void __launch_bounds__(256, 2)
banded_attn_kernel(const __bf16* __restrict__ q16, const __bf16* __restrict__ k16,
                   const __bf16* __restrict__ vt16, const int* __restrict__ mask,
                   float* __restrict__ out)
{
    __shared__ __bf16 Kt[2][64 * PAD];
    __shared__ __bf16 Vt[2][64 * PAD];
    __shared__ __bf16 Pt[4][64 * PAD];
    __shared__ float  Msh[768];

    const int c = blockIdx.x, h = blockIdx.y, b = blockIdx.z;
    const int bh = b * Hn + h;
    const int i0 = c * 256;
    const int jwin0 = i0 - 256;
    const int tid  = threadIdx.x;
    const int wv   = tid >> 6;
    const int lane = tid & 63;
    const int quad = lane >> 4, mrow = lane & 15;

#pragma unroll
    for (int rep = 0; rep < 3; rep++) {
        int idx = rep * 256 + tid;
        int jg  = jwin0 + idx;
        float mv = 0.f;
        if (jg >= 0 && jg < Sn && mask[b * Sn + jg] != 0) mv = -10000.f;
        Msh[idx] = mv;
    }

    // Q B-fragments (loop-invariant): B[k=d][n=q]
    bf16x8 qf[4][2];
    const __bf16* qbase = q16 + (((size_t)bh * Sn + i0 + wv * 64) << 6);
#pragma unroll
    for (int tjq = 0; tjq < 4; tjq++)
#pragma unroll
        for (int kc = 0; kc < 2; kc++)
            qf[tjq][kc] = *(const bf16x8*)(qbase + (16 * tjq + mrow) * 64 + 32 * kc + 8 * quad);

    const int sr = lane >> 3;      // 0..7
    const int sc = lane & 7;       // 16B chunk
    bf16x8 kreg0, kreg1, vreg0, vreg1;
    auto gload = [&](int st) {
        const int j0 = jwin0 + st * 64;
        const int r0 = wv * 16 + sr;
        const int r1 = wv * 16 + 8 + sr;
        int jk0 = j0 + r0; jk0 = jk0 < 0 ? 0 : (jk0 > Sn - 1 ? Sn - 1 : jk0);
        int jk1 = j0 + r1; jk1 = jk1 < 0 ? 0 : (jk1 > Sn - 1 ? Sn - 1 : jk1);
        kreg0 = *(const bf16x8*)&k16[(((size_t)bh * Sn + jk0) << 6) + sc * 8];
        kreg1 = *(const bf16x8*)&k16[(((size_t)bh * Sn + jk1) << 6) + sc * 8];
        int jv = j0 + sc * 8; jv = jv < 0 ? 0 : (jv > Sn - 8 ? Sn - 8 : jv);
        vreg0 = *(const bf16x8*)&vt16[((size_t)bh * 64 + r0) * Sn + jv];
        vreg1 = *(const bf16x8*)&vt16[((size_t)bh * 64 + r1) * Sn + jv];
    };
    auto swrite = [&](int buf) {
        *(bf16x8*)&Kt[buf][(wv * 16 + sr) * PAD + sc * 8]     = kreg0;
        *(bf16x8*)&Kt[buf][(wv * 16 + 8 + sr) * PAD + sc * 8] = kreg1;
        *(bf16x8*)&Vt[buf][(wv * 16 + sr) * PAD + sc * 8]     = vreg0;
        *(bf16x8*)&Vt[buf][(wv * 16 + 8 + sr) * PAD + sc * 8] = vreg1;
    };

    f32x4 acc_o[4][4] = {};
    float lrun[4] = {0.f, 0.f, 0.f, 0.f};
    __bf16* Pw = &Pt[wv][0];

    gload(0);
    swrite(0);
    __syncthreads();

    for (int st = 0; st < 12; st++) {
        const int buf = st & 1;
        if (st + 1 < 12) gload(st + 1);   // issue next global loads early

        if (st >= wv && st <= wv + 8) {
            const __bf16* KtB = &Kt[buf][0];
            const __bf16* VtB = &Vt[buf][0];
            // ---- S^T = K.Q^T, softmax, P -> LDS [query][key] ----
#pragma unroll
            for (int ti = 0; ti < 4; ti++) {
                bf16x8 ak0 = *(const bf16x8*)&KtB[(16 * ti + mrow) * PAD + quad * 8];
                bf16x8 ak1 = *(const bf16x8*)&KtB[(16 * ti + mrow) * PAD + 32 + quad * 8];
                const int y0 = 64 * st + 16 * ti + 4 * quad;
                f32x4 ms4 = *(const f32x4*)&Msh[y0];
#pragma unroll
                for (int tjq = 0; tjq < 4; tjq++) {
                    f32x4 s = {};
                    s = __builtin_amdgcn_mfma_f32_16x16x32_bf16(ak0, qf[tjq][0], s, 0, 0, 0);
                    s = __builtin_amdgcn_mfma_f32_16x16x32_bf16(ak1, qf[tjq][1], s, 0, 0, 0);
                    const int xq = 64 * wv + 16 * tjq + mrow;
                    bf16x4 pk;
                    float psum = 0.f;
#pragma unroll
                    for (int r = 0; r < 4; r++) {
                        const int y = y0 + r;
                        bool ok = ((unsigned)(y - xq) <= 512u) &
                                  ((unsigned)(jwin0 + y) < 4096u);
                        float pv = ok ? __expf(s[r] + ms4[r]) : 0.f;
                        psum += pv;
                        pk[r] = (__bf16)pv;
                    }
                    lrun[tjq] += psum;
                    *(bf16x4*)&Pw[(16 * tjq + mrow) * PAD + 16 * ti + 4 * quad] = pk;
                }
            }
            // ---- O^T += V^T.P^T ----
#pragma unroll
            for (int kc2 = 0; kc2 < 2; kc2++) {
                bf16x8 av[4];
#pragma unroll
                for (int dt = 0; dt < 4; dt++)
                    av[dt] = *(const bf16x8*)&VtB[(16 * dt + mrow) * PAD + kc2 * 32 + quad * 8];
#pragma unroll
                for (int tjq = 0; tjq < 4; tjq++) {
                    bf16x8 pf = *(const bf16x8*)&Pw[(16 * tjq + mrow) * PAD + kc2 * 32 + quad * 8];
#pragma unroll
                    for (int dt = 0; dt < 4; dt++)
                        acc_o[dt][tjq] = __builtin_amdgcn_mfma_f32_16x16x32_bf16(
                            av[dt], pf, acc_o[dt][tjq], 0, 0, 0);
                }
            }
        }

        if (st + 1 < 12) {
            swrite((st + 1) & 1);
            __syncthreads();
        }
    }

    // denominators: sum across quads (keys live across lane bits 4-5)
    float inv[4];
#pragma unroll
    for (int tjq = 0; tjq < 4; tjq++) {
        float l = lrun[tjq];
        l += __shfl_xor(l, 16);
        l += __shfl_xor(l, 32);
        inv[tjq] = 1.0f / l;
    }
    // O^T C-layout: row = d = 16*dt + 4*quad + r, col = q = mrow
#pragma unroll
    for (int dt = 0; dt < 4; dt++)
#pragma unroll
        for (int tjq = 0; tjq < 4; tjq++) {
            f32x4 o = acc_o[dt][tjq];
            o[0] *= inv[tjq]; o[1] *= inv[tjq]; o[2] *= inv[tjq]; o[3] *= inv[tjq];
            float* dst = out + ((size_t)(b * Sn + i0 + wv * 64 + 16 * tjq + mrow)) * En
                             + h * 64 + 16 * dt + 4 * quad;
            *(f32x4*)dst = o;
        }
}

extern "C" void kernel_launch(void* const* d_in, const int* in_sizes, int n_in,
                              void* d_out, int out_size, void* d_ws, size_t ws_size,
                              hipStream_t stream) {
    const float* hs  = (const float*)d_in[0];
    const int*  mask = (const int*)d_in[1];
    const float* qw  = (const float*)d_in[2];
    const float* qb  = (const float*)d_in[3];
    const float* kw  = (const float*)d_in[4];
    const float* kb  = (const float*)d_in[5];
    const float* vw  = (const float*)d_in[6];
    const float* vb  = (const float*)d_in[7];
    float* out = (float*)d_out;

    // Workspace: hs16 16.8MB | w16 6.3MB | q16 16.8MB | k16 16.8MB | vt16 16.8MB
    _Float16* hs16 = (_Float16*)d_ws;
    _Float16* w16  = (_Float16*)((char*)d_ws + (size_t)16777216);
    __bf16*   q16  = (__bf16*)((char*)d_ws + (size_t)23068672);
    __bf16*   k16  = (__bf16*)((char*)d_ws + (size_t)39845888);
    __bf16*   vt16 = (__bf16*)((char*)d_ws + (size_t)56623104);

    cvt_hs_kernel<<<8192, 256, 0, stream>>>(hs, hs16);
    cvt_w_kernel <<<3072, 256, 0, stream>>>(qw, kw, vw, w16);

    dim3 pgridQK(Mtot / 256, 2048 / 256);   // (32, 8): q|k features, 256 blocks
    qkv_mfma_kernel<0><<<pgridQK, 512, 0, stream>>>(hs16, w16, qb, kb, vb,
                                                    q16, k16, vt16, 0);
    dim3 pgridV(Mtot / 256, 1024 / 256);    // (32, 4): v features, 128 blocks
    qkv_mfma_kernel<1><<<pgridV, 512, 0, stream>>>(hs16, w16, qb, kb, vb,
                                                   q16, k16, vt16, 2048);

    dim3 agrid(Sn / 256, Hn, Bn);           // (16, 16, 2)
    banded_attn_kernel<<<agrid, 256, 0, stream>>>(q16, k16, vt16, mask, out);
}

// Round 5
// 225.002 us; speedup vs baseline: 1.0207x; 1.0207x over previous
//
#include <hip/hip_runtime.h>
#include <math.h>

// Problem constants
constexpr int Bn  = 2;
constexpr int Sn  = 4096;
constexpr int En  = 1024;
constexpr int Hn  = 16;
constexpr int Mtot = Bn * Sn;             // 8192
constexpr int Kp  = 1024;                 // GEMM K (fp16 single precision)
constexpr int PAD = 72;                   // LDS row stride (bf16), 144 B = 9x16B

typedef __bf16    bf16x8 __attribute__((ext_vector_type(8)));
typedef __bf16    bf16x4 __attribute__((ext_vector_type(4)));
typedef _Float16  f16x8  __attribute__((ext_vector_type(8)));
typedef _Float16  f16x4  __attribute__((ext_vector_type(4)));
typedef float     f32x4  __attribute__((ext_vector_type(4)));

// ---------------- fp32 -> fp16 conversion ----------------
__global__ void __launch_bounds__(256)
cvt_hs_kernel(const float* __restrict__ hs, _Float16* __restrict__ hs16)
{
    int t = blockIdx.x * 256 + threadIdx.x;
    int m = t >> 8;
    int k = (t & 255) << 2;
    float4 x = *(const float4*)&hs[((size_t)m << 10) + k];
    f16x4 h;
    h[0] = (_Float16)x.x; h[1] = (_Float16)x.y;
    h[2] = (_Float16)x.z; h[3] = (_Float16)x.w;
    *(f16x4*)&hs16[((size_t)m << 10) + k] = h;
}

__global__ void __launch_bounds__(256)
cvt_w_kernel(const float* __restrict__ qw, const float* __restrict__ kw,
             const float* __restrict__ vw, _Float16* __restrict__ w16)
{
    int t = blockIdx.x * 256 + threadIdx.x;
    int gn = t >> 8;
    int k  = (t & 255) << 2;
    int p  = gn >> 10, n = gn & 1023;
    const float* src = (p == 0) ? qw : (p == 1) ? kw : vw;
    float4 x = *(const float4*)&src[((size_t)n << 10) + k];
    f16x4 h;
    h[0] = (_Float16)x.x; h[1] = (_Float16)x.y;
    h[2] = (_Float16)x.z; h[3] = (_Float16)x.w;
    *(f16x4*)&w16[((size_t)gn << 10) + k] = h;
}

// ---------------- QKV projection: 256x256-tile 8-wave MFMA GEMM -------------
// v6: v5's 256^2/8-wave/BK=64 geometry + TRUE counted vmcnt (T4, m218:
// counted-vs-drain0 = +38..73% within the phase structure; v5 drained to 0
// at every tile end, which is why it only reached MfmaUtil 27%).
// Staging is factored into kc-halves so waits never reach 0 in the loop:
//   LDS: As/Bs[buf][kc][256][32] f16 (128 KiB total). Region {A-kc,B-kc} is
//   wave-linear (16 rows x 64B per load) for global_load_lds.
//   p0(t): read kc0 frags (ti0-3 + B) | stage A0,B0(t+1) | bar | 16 MFMA | bar
//   p1(t): read kc0 af(ti4-7)        | stage A1,B1(t+1) | bar | 16 MFMA |
//          vmcnt(8) | bar        <- retires A1B1(t), 5 phases of flight
//   p2(t): read kc1 frags            |                    bar | 16 MFMA | bar
//   p3(t): read kc1 af(ti4-7)        |                    bar | 16 MFMA |
//          vmcnt(4) | bar        <- retires A0B0(t+1), 3 phases of flight
// FIFO audit (per-wave, 4 loads/region, vmcnt retires oldest-first):
//   p1-end: [A1B1(t),A0B0(t+1),A1B1(t+1)]=12 -> vmcnt(8) ok
//   p3-end: [A0B0(t+1),A1B1(t+1)]=8         -> vmcnt(4) ok
// Last tile peeled: vmcnt(0) at its p1 (loads 8 phases old, ~free).
// Bias vectors preloaded BEFORE the prologue so epilogue loads cannot enter
// the vmcnt FIFO mid-loop.
// XOR swizzle: LDS slot s of row r holds global 16B-chunk s^((r>>1)&3)
// (pre-swizzled global source, linear LDS dest); frag read slot =
// quad^((mrow>>1)&3) -> <=2-way bank aliasing (free, m136).
__device__ inline void load_lds16(const void* g, void* s) {
    __builtin_amdgcn_global_load_lds((const __attribute__((address_space(1))) void*)g,
                                     (__attribute__((address_space(3))) void*)s,
                                     16, 0, 0);
}

__device__ inline void block_sync() {
    asm volatile("" ::: "memory");
    __builtin_amdgcn_s_barrier();
    asm volatile("" ::: "memory");
}
__device__ inline void vm_wait8() { asm volatile("s_waitcnt vmcnt(8)" ::: "memory"); }
__device__ inline void vm_wait4() { asm volatile("s_waitcnt vmcnt(4)" ::: "memory"); }
__device__ inline void vm_wait0() { asm volatile("s_waitcnt vmcnt(0)" ::: "memory"); }

template<int PM>   // 0 = q|k (swapped operands), 1 = v
__global__ void __launch_bounds__(512, 2)
qkv_mfma_kernel(const _Float16* __restrict__ A2, const _Float16* __restrict__ B2,
                const float* __restrict__ qb, const float* __restrict__ kb,
                const float* __restrict__ vb,
                __bf16* __restrict__ q16, __bf16* __restrict__ k16,
                __bf16* __restrict__ vt16, int n0base)
{
    __shared__ _Float16 As[2][2][256][32];   // [buf][kc][row][col] 64 KiB
    __shared__ _Float16 Bs[2][2][256][32];   // 64 KiB -> 128 KiB total

    const int tid  = threadIdx.x;
    const int w    = tid >> 6;             // 0..7
    const int lane = tid & 63;
    const int wm   = w >> 2, wn = w & 3;   // 2M x 4N wave grid
    const int mrow = lane & 15, quad = lane >> 4;
    const int m0   = blockIdx.x * 256;             // seq tile
    const int n0   = n0base + blockIdx.y * 256;    // feature tile

    // staging: lane l -> LDS (row base + l>>2, slot l&3); global chunk =
    // (l&3) ^ ((l>>3)&3)  (inverse swizzle on the source, m173 pattern)
    const int subrow = lane >> 2;          // 0..15
    const int gch    = ((lane & 3) ^ ((lane >> 3) & 3)) * 8;   // f16 offset
    const _Float16* Ag = A2 + (size_t)(m0 + w * 32 + subrow) * Kp + gch;
    const _Float16* Bg = B2 + (size_t)(n0 + w * 32 + subrow) * Kp + gch;

    // frag read slot (f16 offset within the 32-col kc region)
    const int sl = (quad ^ ((mrow >> 1) & 3)) * 8;

    f32x4 acc[8][4] = {};

    auto stageA = [&](int kt, int bi, int kc) {
        const size_t goff = (size_t)kt * 64 + kc * 32;
#pragma unroll
        for (int l = 0; l < 2; l++)
            load_lds16(Ag + (size_t)l * 16 * Kp + goff, &As[bi][kc][w * 32 + l * 16][0]);
    };
    auto stageB = [&](int kt, int bi, int kc) {
        const size_t goff = (size_t)kt * 64 + kc * 32;
#pragma unroll
        for (int l = 0; l < 2; l++)
            load_lds16(Bg + (size_t)l * 16 * Kp + goff, &Bs[bi][kc][w * 32 + l * 16][0]);
    };
    auto ladder = [&](const f16x8* AF, const f16x8* BF, int r0) {
        __builtin_amdgcn_s_setprio(1);
#pragma unroll
        for (int ti = 0; ti < 4; ti++)
#pragma unroll
            for (int tj = 0; tj < 4; tj++) {
                if (PM == 0)   // C[m=feature][n=seq]
                    acc[r0 + ti][tj] = __builtin_amdgcn_mfma_f32_16x16x32_f16(
                        BF[tj], AF[ti], acc[r0 + ti][tj], 0, 0, 0);
                else           // C[m=seq][n=feature]
                    acc[r0 + ti][tj] = __builtin_amdgcn_mfma_f32_16x16x32_f16(
                        AF[ti], BF[tj], acc[r0 + ti][tj], 0, 0, 0);
            }
        __builtin_amdgcn_s_setprio(0);
    };

    constexpr int NT = Kp / 64;            // 16 K-tiles

    // Preload epilogue bias so no global loads enter the vmcnt FIFO mid-loop.
    float4 bv4[4];      // PM0: float4 per tj     PM1: .x used per tj
    const int p = n0 >> 10;
    {
        const float* bptr = (p == 0) ? qb : (p == 1) ? kb : vb;
#pragma unroll
        for (int tj = 0; tj < 4; tj++) {
            if (PM == 0) {
                const int fl = (n0 + wn * 64 + tj * 16 + quad * 4) & 1023;
                bv4[tj] = *(const float4*)&bptr[fl];
            } else {
                const int n = (n0 + wn * 64 + tj * 16 + mrow) & 1023;
                bv4[tj].x = bptr[n];
            }
        }
    }

    // Prologue: stage tile 0 fully; retire kc0 (and bias), keep kc1 in flight.
    stageA(0, 0, 0); stageB(0, 0, 0);
    stageA(0, 0, 1); stageB(0, 0, 1);
    vm_wait4();
    block_sync();

    for (int kt = 0; kt < NT; ++kt) {
        const int rb = kt & 1, wb = rb ^ 1;
        const bool pre  = (kt + 1 < NT);
        const bool last = (kt + 1 == NT);
        f16x8 af[4], bf[4];

        // ---- p0: kc0, ti0-3 ----
#pragma unroll
        for (int t = 0; t < 4; t++)
            af[t] = *(const f16x8*)&As[rb][0][wm * 128 + t * 16 + mrow][sl];
#pragma unroll
        for (int t = 0; t < 4; t++)
            bf[t] = *(const f16x8*)&Bs[rb][0][wn * 64 + t * 16 + mrow][sl];
        if (pre) { stageA(kt + 1, wb, 0); stageB(kt + 1, wb, 0); }
        block_sync();
        ladder(af, bf, 0);
        block_sync();

        // ---- p1: kc0, ti4-7 ----
#pragma unroll
        for (int t = 0; t < 4; t++)
            af[t] = *(const f16x8*)&As[rb][0][wm * 128 + 64 + t * 16 + mrow][sl];
        if (pre) { stageA(kt + 1, wb, 1); stageB(kt + 1, wb, 1); }
        block_sync();
        ladder(af, bf, 4);
        if (last) vm_wait0(); else vm_wait8();   // retire A1B1(kt) before p2
        block_sync();

        // ---- p2: kc1, ti0-3 ----
#pragma unroll
        for (int t = 0; t < 4; t++)
            af[t] = *(const f16x8*)&As[rb][1][wm * 128 + t * 16 + mrow][sl];
#pragma unroll
        for (int t = 0; t < 4; t++)
            bf[t] = *(const f16x8*)&Bs[rb][1][wn * 64 + t * 16 + mrow][sl];
        block_sync();
        ladder(af, bf, 0);
        block_sync();

        // ---- p3: kc1, ti4-7 ----
#pragma unroll
        for (int t = 0; t < 4; t++)
            af[t] = *(const f16x8*)&As[rb][1][wm * 128 + 64 + t * 16 + mrow][sl];
        block_sync();
        ladder(af, bf, 4);
        vm_wait4();                              // retire A0B0(kt+1) before p0
        block_sync();
    }

    if (PM == 0) {
        // acc[ti][tj]: row (quad*4+r) = feature, col (mrow) = seq
        __bf16* dst = (p == 0) ? q16 : k16;
        const float scl = (p == 0) ? 0.125f : 1.0f;
#pragma unroll
        for (int ti = 0; ti < 8; ti++) {
            const int m  = m0 + wm * 128 + ti * 16 + mrow;   // seq
            const int bb = m >> 12, ss = m & 4095;
#pragma unroll
            for (int tj = 0; tj < 4; tj++) {
                const int fl = (n0 + wn * 64 + tj * 16 + quad * 4) & 1023;
                const int hh = fl >> 6, dd = fl & 63;        // dd..dd+3
                bf16x4 o;
                o[0] = (__bf16)((acc[ti][tj][0] + bv4[tj].x) * scl);
                o[1] = (__bf16)((acc[ti][tj][1] + bv4[tj].y) * scl);
                o[2] = (__bf16)((acc[ti][tj][2] + bv4[tj].z) * scl);
                o[3] = (__bf16)((acc[ti][tj][3] + bv4[tj].w) * scl);
                *(bf16x4*)&dst[((size_t)(bb * Hn + hh) * Sn + ss) * 64 + dd] = o;
            }
        }
    } else {
        // acc[ti][tj]: row (quad*4+r) = seq, col (mrow) = feature; V^T layout
#pragma unroll
        for (int tj = 0; tj < 4; tj++) {
            const int n  = n0 + wn * 64 + tj * 16 + mrow;
            const float bv = bv4[tj].x;
            const int hh = (n & 1023) >> 6, dd = n & 63;
#pragma unroll
            for (int ti = 0; ti < 8; ti++) {
                const int m  = m0 + wm * 128 + ti * 16 + quad * 4;   // + r
                const int bb = m >> 12, ss = m & 4095;
                bf16x4 pv4;
#pragma unroll
                for (int r = 0; r < 4; r++)
                    pv4[r] = (__bf16)(acc[ti][tj][r] + bv);
                *(bf16x4*)&vt16[((size_t)(bb * Hn + hh) * 64 + dd) * Sn + ss] = pv4;
            }
        }
    }
}

// ---------------- Banded attention: MFMA, double-buffered staging -----------
// Block = 256 queries (4 waves x 64). S^T = K.Q^T ; O^T = V^T.P^T.
// ONE barrier per subtile: compute reads buf[st&1] while regs hold st+1 data;
// writes go to buf[(st+1)&1], whose last readers synced at the st-1 barrier.
__global__ void __launch_bounds__(256, 2)
banded_attn_kernel(const __bf16* __restrict__ q16, const __bf16* __restrict__ k16,
                   const __bf16* __restrict__ vt16, const int* __restrict__ mask,
                   float* __restrict__ out)
{
    __shared__ __bf16 Kt[2][64 * PAD];
    __shared__ __bf16 Vt[2][64 * PAD];
    __shared__ __bf16 Pt[4][64 * PAD];
    __shared__ float  Msh[768];

    const int c = blockIdx.x, h = blockIdx.y, b = blockIdx.z;
    const int bh = b * Hn + h;
    const int i0 = c * 256;
    const int jwin0 = i0 - 256;
    const int tid  = threadIdx.x;
    const int wv   = tid >> 6;
    const int lane = tid & 63;
    const int quad = lane >> 4, mrow = lane & 15;

#pragma unroll
    for (int rep = 0; rep < 3; rep++) {
        int idx = rep * 256 + tid;
        int jg  = jwin0 + idx;
        float mv = 0.f;
        if (jg >= 0 && jg < Sn && mask[b * Sn + jg] != 0) mv = -10000.f;
        Msh[idx] = mv;
    }

    // Q B-fragments (loop-invariant): B[k=d][n=q]
    bf16x8 qf[4][2];
    const __bf16* qbase = q16 + (((size_t)bh * Sn + i0 + wv * 64) << 6);
#pragma unroll
    for (int tjq = 0; tjq < 4; tjq++)
#pragma unroll
        for (int kc = 0; kc < 2; kc++)
            qf[tjq][kc] = *(const bf16x8*)(qbase + (16 * tjq + mrow) * 64 + 32 * kc + 8 * quad);

    const int sr = lane >> 3;      // 0..7
    const int sc = lane & 7;       // 16B chunk
    bf16x8 kreg0, kreg1, vreg0, vreg1;
    auto gload = [&](int st) {
        const int j0 = jwin0 + st * 64;
        const int r0 = wv * 16 + sr;
        const int r1 = wv * 16 + 8 + sr;
        int jk0 = j0 + r0; jk0 = jk0 < 0 ? 0 : (jk0 > Sn - 1 ? Sn - 1 : jk0);
        int jk1 = j0 + r1; jk1 = jk1 < 0 ? 0 : (jk1 > Sn - 1 ? Sn - 1 : jk1);
        kreg0 = *(const bf16x8*)&k16[(((size_t)bh * Sn + jk0) << 6) + sc * 8];
        kreg1 = *(const bf16x8*)&k16[(((size_t)bh * Sn + jk1) << 6) + sc * 8];
        int jv = j0 + sc * 8; jv = jv < 0 ? 0 : (jv > Sn - 8 ? Sn - 8 : jv);
        vreg0 = *(const bf16x8*)&vt16[((size_t)bh * 64 + r0) * Sn + jv];
        vreg1 = *(const bf16x8*)&vt16[((size_t)bh * 64 + r1) * Sn + jv];
    };
    auto swrite = [&](int buf) {
        *(bf16x8*)&Kt[buf][(wv * 16 + sr) * PAD + sc * 8]     = kreg0;
        *(bf16x8*)&Kt[buf][(wv * 16 + 8 + sr) * PAD + sc * 8] = kreg1;
        *(bf16x8*)&Vt[buf][(wv * 16 + sr) * PAD + sc * 8]     = vreg0;
        *(bf16x8*)&Vt[buf][(wv * 16 + 8 + sr) * PAD + sc * 8] = vreg1;
    };

    f32x4 acc_o[4][4] = {};
    float lrun[4] = {0.f, 0.f, 0.f, 0.f};
    __bf16* Pw = &Pt[wv][0];

    gload(0);
    swrite(0);
    __syncthreads();

    for (int st = 0; st < 12; st++) {
        const int buf = st & 1;
        if (st + 1 < 12) gload(st + 1);   // issue next global loads early

        if (st >= wv && st <= wv + 8) {
            const __bf16* KtB = &Kt[buf][0];
            const __bf16* VtB = &Vt[buf][0];
            // ---- S^T = K.Q^T, softmax, P -> LDS [query][key] ----
#pragma unroll
            for (int ti = 0; ti < 4; ti++) {
                bf16x8 ak0 = *(const bf16x8*)&KtB[(16 * ti + mrow) * PAD + quad * 8];
                bf16x8 ak1 = *(const bf16x8*)&KtB[(16 * ti + mrow) * PAD + 32 + quad * 8];
                const int y0 = 64 * st + 16 * ti + 4 * quad;
                f32x4 ms4 = *(const f32x4*)&Msh[y0];
#pragma unroll
                for (int tjq = 0; tjq < 4; tjq++) {
                    f32x4 s = {};
                    s = __builtin_amdgcn_mfma_f32_16x16x32_bf16(ak0, qf[tjq][0], s, 0, 0, 0);
                    s = __builtin_amdgcn_mfma_f32_16x16x32_bf16(ak1, qf[tjq][1], s, 0, 0, 0);
                    const int xq = 64 * wv + 16 * tjq + mrow;
                    bf16x4 pk;
                    float psum = 0.f;
#pragma unroll
                    for (int r = 0; r < 4; r++) {
                        const int y = y0 + r;
                        bool ok = ((unsigned)(y - xq) <= 512u) &
                                  ((unsigned)(jwin0 + y) < 4096u);
                        float pv = ok ? __expf(s[r] + ms4[r]) : 0.f;
                        psum += pv;
                        pk[r] = (__bf16)pv;
                    }
                    lrun[tjq] += psum;
                    *(bf16x4*)&Pw[(16 * tjq + mrow) * PAD + 16 * ti + 4 * quad] = pk;
                }
            }
            // ---- O^T += V^T.P^T ----
#pragma unroll
            for (int kc2 = 0; kc2 < 2; kc2++) {
                bf16x8 av[4];
#pragma unroll
                for (int dt = 0; dt < 4; dt++)
                    av[dt] = *(const bf16x8*)&VtB[(16 * dt + mrow) * PAD + kc2 * 32 + quad * 8];
#pragma unroll
                for (int tjq = 0; tjq < 4; tjq++) {
                    bf16x8 pf = *(const bf16x8*)&Pw[(16 * tjq + mrow) * PAD + kc2 * 32 + quad * 8];
#pragma unroll
                    for (int dt = 0; dt < 4; dt++)
                        acc_o[dt][tjq] = __builtin_amdgcn_mfma_f32_16x16x32_bf16(
                            av[dt], pf, acc_o[dt][tjq], 0, 0, 0);
                }
            }
        }

        if (st + 1 < 12) {
            swrite((st + 1) & 1);
            __syncthreads();
        }
    }

    // denominators: sum across quads (keys live across lane bits 4-5)
    float inv[4];
#pragma unroll
    for (int tjq = 0; tjq < 4; tjq++) {
        float l = lrun[tjq];
        l += __shfl_xor(l, 16);
        l += __shfl_xor(l, 32);
        inv[tjq] = 1.0f / l;
    }
    // O^T C-layout: row = d = 16*dt + 4*quad + r, col = q = mrow
#pragma unroll
    for (int dt = 0; dt < 4; dt++)
#pragma unroll
        for (int tjq = 0; tjq < 4; tjq++) {
            f32x4 o = acc_o[dt][tjq];
            o[0] *= inv[tjq]; o[1] *= inv[tjq]; o[2] *= inv[tjq]; o[3] *= inv[tjq];
            float* dst = out + ((size_t)(b * Sn + i0 + wv * 64 + 16 * tjq + mrow)) * En
                             + h * 64 + 16 * dt + 4 * quad;
            *(f32x4*)dst = o;
        }
}

extern "C" void kernel_launch(void* const* d_in, const int* in_sizes, int n_in,
                              void* d_out, int out_size, void* d_ws, size_t ws_size,
                              hipStream_t stream) {
    const float* hs  = (const float*)d_in[0];
    const int*  mask = (const int*)d_in[1];
    const float* qw  = (const float*)d_in[2];
    const float* qb  = (const float*)d_in[3];
    const float* kw  = (const float*)d_in[4];
    const float* kb  = (const float*)d_in[5];
    const float* vw  = (const float*)d_in[6];
    const float* vb  = (const float*)d_in[7];
    float* out = (float*)d_out;

    // Workspace: hs16 16.8MB | w16 6.3MB | q16 16.8MB | k16 16.8MB | vt16 16.8MB
    _Float16* hs16 = (_Float16*)d_ws;
    _Float16* w16  = (_Float16*)((char*)d_ws + (size_t)16777216);
    __bf16*   q16  = (__bf16*)((char*)d_ws + (size_t)23068672);
    __bf16*   k16  = (__bf16*)((char*)d_ws + (size_t)39845888);
    __bf16*   vt16 = (__bf16*)((char*)d_ws + (size_t)56623104);

    cvt_hs_kernel<<<8192, 256, 0, stream>>>(hs, hs16);
    cvt_w_kernel <<<3072, 256, 0, stream>>>(qw, kw, vw, w16);

    dim3 pgridQK(Mtot / 256, 2048 / 256);   // (32, 8): q|k features, 256 blocks
    qkv_mfma_kernel<0><<<pgridQK, 512, 0, stream>>>(hs16, w16, qb, kb, vb,
                                                    q16, k16, vt16, 0);
    dim3 pgridV(Mtot / 256, 1024 / 256);    // (32, 4): v features, 128 blocks
    qkv_mfma_kernel<1><<<pgridV, 512, 0, stream>>>(hs16, w16, qb, kb, vb,
                                                   q16, k16, vt16, 2048);

    dim3 agrid(Sn / 256, Hn, Bn);           // (16, 16, 2)
    banded_attn_kernel<<<agrid, 256, 0, stream>>>(q16, k16, vt16, mask, out);
}

// Round 6
// 220.797 us; speedup vs baseline: 1.0402x; 1.0190x over previous
//
#include <hip/hip_runtime.h>
#include <math.h>

// Problem constants
constexpr int Bn  = 2;
constexpr int Sn  = 4096;
constexpr int En  = 1024;
constexpr int Hn  = 16;
constexpr int Mtot = Bn * Sn;             // 8192
constexpr int Kp  = 1024;                 // GEMM K (fp16 single precision)
constexpr int PAD = 72;                   // LDS row stride (bf16), 144 B = 9x16B

typedef __bf16    bf16x8 __attribute__((ext_vector_type(8)));
typedef __bf16    bf16x4 __attribute__((ext_vector_type(4)));
typedef _Float16  f16x8  __attribute__((ext_vector_type(8)));
typedef _Float16  f16x4  __attribute__((ext_vector_type(4)));
typedef float     f32x4  __attribute__((ext_vector_type(4)));

// ---------------- fp32 -> fp16 conversion (single fused dispatch) -----------
__global__ void __launch_bounds__(256)
cvt_all_kernel(const float* __restrict__ hs,
               const float* __restrict__ qw, const float* __restrict__ kw,
               const float* __restrict__ vw,
               _Float16* __restrict__ hs16, _Float16* __restrict__ w16)
{
    const int bid = blockIdx.x;
    if (bid < 8192) {
        int t = bid * 256 + threadIdx.x;
        int m = t >> 8;
        int k = (t & 255) << 2;
        float4 x = *(const float4*)&hs[((size_t)m << 10) + k];
        f16x4 h;
        h[0] = (_Float16)x.x; h[1] = (_Float16)x.y;
        h[2] = (_Float16)x.z; h[3] = (_Float16)x.w;
        *(f16x4*)&hs16[((size_t)m << 10) + k] = h;
    } else {
        int t = (bid - 8192) * 256 + threadIdx.x;
        int gn = t >> 8;
        int k  = (t & 255) << 2;
        int p  = gn >> 10, n = gn & 1023;
        const float* src = (p == 0) ? qw : (p == 1) ? kw : vw;
        float4 x = *(const float4*)&src[((size_t)n << 10) + k];
        f16x4 h;
        h[0] = (_Float16)x.x; h[1] = (_Float16)x.y;
        h[2] = (_Float16)x.z; h[3] = (_Float16)x.w;
        *(f16x4*)&w16[((size_t)gn << 10) + k] = h;
    }
}

// ---------------- QKV projection: 256x256-tile 8-wave MFMA GEMM -------------
// v7 = v6's verified counted-vmcnt schedule (T4: vmcnt(8)/vmcnt(4), never 0
// in the loop -- this took qkv<0> 51.7 -> <48 us) with the q|k and v variants
// FUSED into one dispatch: grid (32,12); blockIdx.y<8 -> qk path (swapped
// MFMA operands), else v path. Top-level UNIFORM branch into two disjoint
// template bodies (regalloc = max of paths, not r1's interleaved sum; LDS
// 128KB pins occupancy at 1 block/CU regardless, so VGPR growth is free).
// Why fuse: qkv<1>'s 128-block grid left half the GPU idle for ~46us; fused,
// v-blocks back-fill CUs as qk-blocks finish, and one launch gap disappears.
__device__ inline void load_lds16(const void* g, void* s) {
    __builtin_amdgcn_global_load_lds((const __attribute__((address_space(1))) void*)g,
                                     (__attribute__((address_space(3))) void*)s,
                                     16, 0, 0);
}

__device__ inline void block_sync() {
    asm volatile("" ::: "memory");
    __builtin_amdgcn_s_barrier();
    asm volatile("" ::: "memory");
}
__device__ inline void vm_wait8() { asm volatile("s_waitcnt vmcnt(8)" ::: "memory"); }
__device__ inline void vm_wait4() { asm volatile("s_waitcnt vmcnt(4)" ::: "memory"); }
__device__ inline void vm_wait0() { asm volatile("s_waitcnt vmcnt(0)" ::: "memory"); }

typedef _Float16 ldsAB_t[2][2][256][32];   // [buf][kc][row][col]

template<int PM>   // 0 = q|k (swapped operands), 1 = v
__device__ __forceinline__ void
qkv_body(ldsAB_t& As, ldsAB_t& Bs,
         const _Float16* __restrict__ A2, const _Float16* __restrict__ B2,
         const float* __restrict__ qb, const float* __restrict__ kb,
         const float* __restrict__ vb,
         __bf16* __restrict__ q16, __bf16* __restrict__ k16,
         __bf16* __restrict__ vt16, int n0)
{
    const int tid  = threadIdx.x;
    const int w    = tid >> 6;             // 0..7
    const int lane = tid & 63;
    const int wm   = w >> 2, wn = w & 3;   // 2M x 4N wave grid
    const int mrow = lane & 15, quad = lane >> 4;
    const int m0   = blockIdx.x * 256;     // seq tile

    // staging: lane l -> LDS (row base + l>>2, slot l&3); global chunk =
    // (l&3) ^ ((l>>3)&3)  (inverse swizzle on the source, m173 pattern)
    const int subrow = lane >> 2;          // 0..15
    const int gch    = ((lane & 3) ^ ((lane >> 3) & 3)) * 8;   // f16 offset
    const _Float16* Ag = A2 + (size_t)(m0 + w * 32 + subrow) * Kp + gch;
    const _Float16* Bg = B2 + (size_t)(n0 + w * 32 + subrow) * Kp + gch;

    // frag read slot (f16 offset within the 32-col kc region)
    const int sl = (quad ^ ((mrow >> 1) & 3)) * 8;

    f32x4 acc[8][4] = {};

    auto stageA = [&](int kt, int bi, int kc) {
        const size_t goff = (size_t)kt * 64 + kc * 32;
#pragma unroll
        for (int l = 0; l < 2; l++)
            load_lds16(Ag + (size_t)l * 16 * Kp + goff, &As[bi][kc][w * 32 + l * 16][0]);
    };
    auto stageB = [&](int kt, int bi, int kc) {
        const size_t goff = (size_t)kt * 64 + kc * 32;
#pragma unroll
        for (int l = 0; l < 2; l++)
            load_lds16(Bg + (size_t)l * 16 * Kp + goff, &Bs[bi][kc][w * 32 + l * 16][0]);
    };
    auto ladder = [&](const f16x8* AF, const f16x8* BF, int r0) {
        __builtin_amdgcn_s_setprio(1);
#pragma unroll
        for (int ti = 0; ti < 4; ti++)
#pragma unroll
            for (int tj = 0; tj < 4; tj++) {
                if (PM == 0)   // C[m=feature][n=seq]
                    acc[r0 + ti][tj] = __builtin_amdgcn_mfma_f32_16x16x32_f16(
                        BF[tj], AF[ti], acc[r0 + ti][tj], 0, 0, 0);
                else           // C[m=seq][n=feature]
                    acc[r0 + ti][tj] = __builtin_amdgcn_mfma_f32_16x16x32_f16(
                        AF[ti], BF[tj], acc[r0 + ti][tj], 0, 0, 0);
            }
        __builtin_amdgcn_s_setprio(0);
    };

    constexpr int NT = Kp / 64;            // 16 K-tiles

    // Preload epilogue bias so no global loads enter the vmcnt FIFO mid-loop.
    float4 bv4[4];      // PM0: float4 per tj     PM1: .x used per tj
    const int p = n0 >> 10;
    {
        const float* bptr = (p == 0) ? qb : (p == 1) ? kb : vb;
#pragma unroll
        for (int tj = 0; tj < 4; tj++) {
            if (PM == 0) {
                const int fl = (n0 + wn * 64 + tj * 16 + quad * 4) & 1023;
                bv4[tj] = *(const float4*)&bptr[fl];
            } else {
                const int n = (n0 + wn * 64 + tj * 16 + mrow) & 1023;
                bv4[tj].x = bptr[n];
            }
        }
    }

    // Prologue: stage tile 0 fully; retire kc0 (and bias), keep kc1 in flight.
    stageA(0, 0, 0); stageB(0, 0, 0);
    stageA(0, 0, 1); stageB(0, 0, 1);
    vm_wait4();
    block_sync();

    for (int kt = 0; kt < NT; ++kt) {
        const int rb = kt & 1, wb = rb ^ 1;
        const bool pre  = (kt + 1 < NT);
        const bool last = (kt + 1 == NT);
        f16x8 af[4], bf[4];

        // ---- p0: kc0, ti0-3 ----
#pragma unroll
        for (int t = 0; t < 4; t++)
            af[t] = *(const f16x8*)&As[rb][0][wm * 128 + t * 16 + mrow][sl];
#pragma unroll
        for (int t = 0; t < 4; t++)
            bf[t] = *(const f16x8*)&Bs[rb][0][wn * 64 + t * 16 + mrow][sl];
        if (pre) { stageA(kt + 1, wb, 0); stageB(kt + 1, wb, 0); }
        block_sync();
        ladder(af, bf, 0);
        block_sync();

        // ---- p1: kc0, ti4-7 ----
#pragma unroll
        for (int t = 0; t < 4; t++)
            af[t] = *(const f16x8*)&As[rb][0][wm * 128 + 64 + t * 16 + mrow][sl];
        if (pre) { stageA(kt + 1, wb, 1); stageB(kt + 1, wb, 1); }
        block_sync();
        ladder(af, bf, 4);
        if (last) vm_wait0(); else vm_wait8();   // retire A1B1(kt) before p2
        block_sync();

        // ---- p2: kc1, ti0-3 ----
#pragma unroll
        for (int t = 0; t < 4; t++)
            af[t] = *(const f16x8*)&As[rb][1][wm * 128 + t * 16 + mrow][sl];
#pragma unroll
        for (int t = 0; t < 4; t++)
            bf[t] = *(const f16x8*)&Bs[rb][1][wn * 64 + t * 16 + mrow][sl];
        block_sync();
        ladder(af, bf, 0);
        block_sync();

        // ---- p3: kc1, ti4-7 ----
#pragma unroll
        for (int t = 0; t < 4; t++)
            af[t] = *(const f16x8*)&As[rb][1][wm * 128 + 64 + t * 16 + mrow][sl];
        block_sync();
        ladder(af, bf, 4);
        vm_wait4();                              // retire A0B0(kt+1) before p0
        block_sync();
    }

    if (PM == 0) {
        // acc[ti][tj]: row (quad*4+r) = feature, col (mrow) = seq
        __bf16* dst = (p == 0) ? q16 : k16;
        const float scl = (p == 0) ? 0.125f : 1.0f;
#pragma unroll
        for (int ti = 0; ti < 8; ti++) {
            const int m  = m0 + wm * 128 + ti * 16 + mrow;   // seq
            const int bb = m >> 12, ss = m & 4095;
#pragma unroll
            for (int tj = 0; tj < 4; tj++) {
                const int fl = (n0 + wn * 64 + tj * 16 + quad * 4) & 1023;
                const int hh = fl >> 6, dd = fl & 63;        // dd..dd+3
                bf16x4 o;
                o[0] = (__bf16)((acc[ti][tj][0] + bv4[tj].x) * scl);
                o[1] = (__bf16)((acc[ti][tj][1] + bv4[tj].y) * scl);
                o[2] = (__bf16)((acc[ti][tj][2] + bv4[tj].z) * scl);
                o[3] = (__bf16)((acc[ti][tj][3] + bv4[tj].w) * scl);
                *(bf16x4*)&dst[((size_t)(bb * Hn + hh) * Sn + ss) * 64 + dd] = o;
            }
        }
    } else {
        // acc[ti][tj]: row (quad*4+r) = seq, col (mrow) = feature; V^T layout
#pragma unroll
        for (int tj = 0; tj < 4; tj++) {
            const int n  = n0 + wn * 64 + tj * 16 + mrow;
            const float bv = bv4[tj].x;
            const int hh = (n & 1023) >> 6, dd = n & 63;
#pragma unroll
            for (int ti = 0; ti < 8; ti++) {
                const int m  = m0 + wm * 128 + ti * 16 + quad * 4;   // + r
                const int bb = m >> 12, ss = m & 4095;
                bf16x4 pv4;
#pragma unroll
                for (int r = 0; r < 4; r++)
                    pv4[r] = (__bf16)(acc[ti][tj][r] + bv);
                *(bf16x4*)&vt16[((size_t)(bb * Hn + hh) * 64 + dd) * Sn + ss] = pv4;
            }
        }
    }
}

__global__ void __launch_bounds__(512, 2)
qkv_fused_kernel(const _Float16* __restrict__ A2, const _Float16* __restrict__ B2,
                 const float* __restrict__ qb, const float* __restrict__ kb,
                 const float* __restrict__ vb,
                 __bf16* __restrict__ q16, __bf16* __restrict__ k16,
                 __bf16* __restrict__ vt16)
{
    __shared__ ldsAB_t As, Bs;             // 128 KiB total
    const int by = blockIdx.y;
    if (by < 8)
        qkv_body<0>(As, Bs, A2, B2, qb, kb, vb, q16, k16, vt16, by * 256);
    else
        qkv_body<1>(As, Bs, A2, B2, qb, kb, vb, q16, k16, vt16,
                    2048 + (by - 8) * 256);
}

// ---------------- Banded attention: MFMA, double-buffered staging -----------
// Block = 256 queries (4 waves x 64). S^T = K.Q^T ; O^T = V^T.P^T.
// v7 softmax-VALU cuts (r5: VALUBusy 36% vs MfmaUtil 15% -- softmax is the
// pipe): (a) key-range validity folded into the Msh additive mask (-1e4 ->
// exp underflows to exact 0, same semantics); (b) QK accumulator INITIALIZED
// with ms4 (MFMA C-in) instead of a post-add; (c) band check (y-xq)<=512 is
// always-true for interior subtiles (st-wv in [1,7] => y-xq in [1,511]) ->
// evaluated only on the two edge subtiles (wave-uniform branch).
__global__ void __launch_bounds__(256, 2)
banded_attn_kernel(const __bf16* __restrict__ q16, const __bf16* __restrict__ k16,
                   const __bf16* __restrict__ vt16, const int* __restrict__ mask,
                   float* __restrict__ out)
{
    __shared__ __bf16 Kt[2][64 * PAD];
    __shared__ __bf16 Vt[2][64 * PAD];
    __shared__ __bf16 Pt[4][64 * PAD];
    __shared__ float  Msh[768];

    const int c = blockIdx.x, h = blockIdx.y, b = blockIdx.z;
    const int bh = b * Hn + h;
    const int i0 = c * 256;
    const int jwin0 = i0 - 256;
    const int tid  = threadIdx.x;
    const int wv   = tid >> 6;
    const int lane = tid & 63;
    const int quad = lane >> 4, mrow = lane & 15;

#pragma unroll
    for (int rep = 0; rep < 3; rep++) {
        int idx = rep * 256 + tid;
        int jg  = jwin0 + idx;
        float mv = -10000.f;                     // out-of-range keys -> exp = 0
        if (jg >= 0 && jg < Sn)
            mv = (mask[b * Sn + jg] != 0) ? -10000.f : 0.f;
        Msh[idx] = mv;
    }

    // Q B-fragments (loop-invariant): B[k=d][n=q]
    bf16x8 qf[4][2];
    const __bf16* qbase = q16 + (((size_t)bh * Sn + i0 + wv * 64) << 6);
#pragma unroll
    for (int tjq = 0; tjq < 4; tjq++)
#pragma unroll
        for (int kc = 0; kc < 2; kc++)
            qf[tjq][kc] = *(const bf16x8*)(qbase + (16 * tjq + mrow) * 64 + 32 * kc + 8 * quad);

    const int sr = lane >> 3;      // 0..7
    const int sc = lane & 7;       // 16B chunk
    bf16x8 kreg0, kreg1, vreg0, vreg1;
    auto gload = [&](int st) {
        const int j0 = jwin0 + st * 64;
        const int r0 = wv * 16 + sr;
        const int r1 = wv * 16 + 8 + sr;
        int jk0 = j0 + r0; jk0 = jk0 < 0 ? 0 : (jk0 > Sn - 1 ? Sn - 1 : jk0);
        int jk1 = j0 + r1; jk1 = jk1 < 0 ? 0 : (jk1 > Sn - 1 ? Sn - 1 : jk1);
        kreg0 = *(const bf16x8*)&k16[(((size_t)bh * Sn + jk0) << 6) + sc * 8];
        kreg1 = *(const bf16x8*)&k16[(((size_t)bh * Sn + jk1) << 6) + sc * 8];
        int jv = j0 + sc * 8; jv = jv < 0 ? 0 : (jv > Sn - 8 ? Sn - 8 : jv);
        vreg0 = *(const bf16x8*)&vt16[((size_t)bh * 64 + r0) * Sn + jv];
        vreg1 = *(const bf16x8*)&vt16[((size_t)bh * 64 + r1) * Sn + jv];
    };
    auto swrite = [&](int buf) {
        *(bf16x8*)&Kt[buf][(wv * 16 + sr) * PAD + sc * 8]     = kreg0;
        *(bf16x8*)&Kt[buf][(wv * 16 + 8 + sr) * PAD + sc * 8] = kreg1;
        *(bf16x8*)&Vt[buf][(wv * 16 + sr) * PAD + sc * 8]     = vreg0;
        *(bf16x8*)&Vt[buf][(wv * 16 + 8 + sr) * PAD + sc * 8] = vreg1;
    };

    f32x4 acc_o[4][4] = {};
    float lrun[4] = {0.f, 0.f, 0.f, 0.f};
    __bf16* Pw = &Pt[wv][0];

    gload(0);
    swrite(0);
    __syncthreads();

    for (int st = 0; st < 12; st++) {
        const int buf = st & 1;
        if (st + 1 < 12) gload(st + 1);   // issue next global loads early

        if (st >= wv && st <= wv + 8) {
            const __bf16* KtB = &Kt[buf][0];
            const __bf16* VtB = &Vt[buf][0];
            const bool edge = (st == wv) || (st == wv + 8);
            // ---- S^T = K.Q^T, softmax, P -> LDS [query][key] ----
#pragma unroll
            for (int ti = 0; ti < 4; ti++) {
                bf16x8 ak0 = *(const bf16x8*)&KtB[(16 * ti + mrow) * PAD + quad * 8];
                bf16x8 ak1 = *(const bf16x8*)&KtB[(16 * ti + mrow) * PAD + 32 + quad * 8];
                const int y0 = 64 * st + 16 * ti + 4 * quad;
                const f32x4 ms4 = *(const f32x4*)&Msh[y0];
#pragma unroll
                for (int tjq = 0; tjq < 4; tjq++) {
                    f32x4 s = ms4;    // additive mask as MFMA C-in
                    s = __builtin_amdgcn_mfma_f32_16x16x32_bf16(ak0, qf[tjq][0], s, 0, 0, 0);
                    s = __builtin_amdgcn_mfma_f32_16x16x32_bf16(ak1, qf[tjq][1], s, 0, 0, 0);
                    bf16x4 pk;
                    float psum = 0.f;
                    if (edge) {
                        const int xq = 64 * wv + 16 * tjq + mrow;
#pragma unroll
                        for (int r = 0; r < 4; r++) {
                            bool ok = ((unsigned)(y0 + r - xq) <= 512u);
                            float pv = ok ? __expf(s[r]) : 0.f;
                            psum += pv;
                            pk[r] = (__bf16)pv;
                        }
                    } else {
                        // interior subtile: band always satisfied, bounds in Msh
#pragma unroll
                        for (int r = 0; r < 4; r++) {
                            float pv = __expf(s[r]);
                            psum += pv;
                            pk[r] = (__bf16)pv;
                        }
                    }
                    lrun[tjq] += psum;
                    *(bf16x4*)&Pw[(16 * tjq + mrow) * PAD + 16 * ti + 4 * quad] = pk;
                }
            }
            // ---- O^T += V^T.P^T ----
#pragma unroll
            for (int kc2 = 0; kc2 < 2; kc2++) {
                bf16x8 av[4];
#pragma unroll
                for (int dt = 0; dt < 4; dt++)
                    av[dt] = *(const bf16x8*)&VtB[(16 * dt + mrow) * PAD + kc2 * 32 + quad * 8];
#pragma unroll
                for (int tjq = 0; tjq < 4; tjq++) {
                    bf16x8 pf = *(const bf16x8*)&Pw[(16 * tjq + mrow) * PAD + kc2 * 32 + quad * 8];
#pragma unroll
                    for (int dt = 0; dt < 4; dt++)
                        acc_o[dt][tjq] = __builtin_amdgcn_mfma_f32_16x16x32_bf16(
                            av[dt], pf, acc_o[dt][tjq], 0, 0, 0);
                }
            }
        }

        if (st + 1 < 12) {
            swrite((st + 1) & 1);
            __syncthreads();
        }
    }

    // denominators: sum across quads (keys live across lane bits 4-5)
    float inv[4];
#pragma unroll
    for (int tjq = 0; tjq < 4; tjq++) {
        float l = lrun[tjq];
        l += __shfl_xor(l, 16);
        l += __shfl_xor(l, 32);
        inv[tjq] = 1.0f / l;
    }
    // O^T C-layout: row = d = 16*dt + 4*quad + r, col = q = mrow
#pragma unroll
    for (int dt = 0; dt < 4; dt++)
#pragma unroll
        for (int tjq = 0; tjq < 4; tjq++) {
            f32x4 o = acc_o[dt][tjq];
            o[0] *= inv[tjq]; o[1] *= inv[tjq]; o[2] *= inv[tjq]; o[3] *= inv[tjq];
            float* dst = out + ((size_t)(b * Sn + i0 + wv * 64 + 16 * tjq + mrow)) * En
                             + h * 64 + 16 * dt + 4 * quad;
            *(f32x4*)dst = o;
        }
}

extern "C" void kernel_launch(void* const* d_in, const int* in_sizes, int n_in,
                              void* d_out, int out_size, void* d_ws, size_t ws_size,
                              hipStream_t stream) {
    const float* hs  = (const float*)d_in[0];
    const int*  mask = (const int*)d_in[1];
    const float* qw  = (const float*)d_in[2];
    const float* qb  = (const float*)d_in[3];
    const float* kw  = (const float*)d_in[4];
    const float* kb  = (const float*)d_in[5];
    const float* vw  = (const float*)d_in[6];
    const float* vb  = (const float*)d_in[7];
    float* out = (float*)d_out;

    // Workspace: hs16 16.8MB | w16 6.3MB | q16 16.8MB | k16 16.8MB | vt16 16.8MB
    _Float16* hs16 = (_Float16*)d_ws;
    _Float16* w16  = (_Float16*)((char*)d_ws + (size_t)16777216);
    __bf16*   q16  = (__bf16*)((char*)d_ws + (size_t)23068672);
    __bf16*   k16  = (__bf16*)((char*)d_ws + (size_t)39845888);
    __bf16*   vt16 = (__bf16*)((char*)d_ws + (size_t)56623104);

    cvt_all_kernel<<<8192 + 3072, 256, 0, stream>>>(hs, qw, kw, vw, hs16, w16);

    dim3 pgrid(Mtot / 256, 12);             // (32, 12): y<8 = q|k, y>=8 = v
    qkv_fused_kernel<<<pgrid, 512, 0, stream>>>(hs16, w16, qb, kb, vb,
                                                q16, k16, vt16);

    dim3 agrid(Sn / 256, Hn, Bn);           // (16, 16, 2)
    banded_attn_kernel<<<agrid, 256, 0, stream>>>(q16, k16, vt16, mask, out);
}